// Round 1
// baseline (707.219 us; speedup 1.0000x reference)
//
#include <hip/hip_runtime.h>

#define NPIX 4096
#define SCALE 0.125f

// ---------------------------------------------------------------------------
// GEMM: C[b][M][N] = A[M][K] * B[b][K][N] (+ optional bias[M])
// BM=BN=128, BK=16, 256 threads, 8x8 microtile, float4 LDS reads.
// ---------------------------------------------------------------------------
template <bool HAS_BIAS>
__global__ __launch_bounds__(256) void gemm_kernel(
    const float* __restrict__ A, const float* __restrict__ B,
    float* __restrict__ C, const float* __restrict__ bias,
    int M, int N, int K, long sB, long sC) {
  __shared__ float As[16][128];
  __shared__ float Bs[16][128];
  const float* Bp = B + (long)blockIdx.z * sB;
  float* Cp = C + (long)blockIdx.z * sC;
  const int n0 = blockIdx.x * 128;
  const int m0 = blockIdx.y * 128;
  const int tid = threadIdx.x;
  const int tx = tid & 15, ty = tid >> 4;

  float acc[8][8];
#pragma unroll
  for (int i = 0; i < 8; i++)
#pragma unroll
    for (int j = 0; j < 8; j++) acc[i][j] = 0.f;

  for (int k0 = 0; k0 < K; k0 += 16) {
    // stage A tile (128 rows x 16 k), transposed into As[k][m]
#pragma unroll
    for (int p = 0; p < 2; p++) {
      int m = (tid >> 2) + p * 64;
      int kk = (tid & 3) * 4;
      float4 av = *(const float4*)&A[(long)(m0 + m) * K + k0 + kk];
      As[kk + 0][m] = av.x;
      As[kk + 1][m] = av.y;
      As[kk + 2][m] = av.z;
      As[kk + 3][m] = av.w;
    }
    // stage B tile (16 k x 128 n)
#pragma unroll
    for (int p = 0; p < 2; p++) {
      int idx = tid + p * 256;
      int row = idx >> 5;
      int c4 = (idx & 31) * 4;
      *(float4*)&Bs[row][c4] = *(const float4*)&Bp[(long)(k0 + row) * N + n0 + c4];
    }
    __syncthreads();
#pragma unroll
    for (int kk = 0; kk < 16; kk++) {
      float a[8], bv[8];
      *(float4*)&a[0] = *(const float4*)&As[kk][ty * 8];
      *(float4*)&a[4] = *(const float4*)&As[kk][ty * 8 + 4];
      *(float4*)&bv[0] = *(const float4*)&Bs[kk][tx * 8];
      *(float4*)&bv[4] = *(const float4*)&Bs[kk][tx * 8 + 4];
#pragma unroll
      for (int i = 0; i < 8; i++)
#pragma unroll
        for (int j = 0; j < 8; j++) acc[i][j] = fmaf(a[i], bv[j], acc[i][j]);
    }
    __syncthreads();
  }

#pragma unroll
  for (int i = 0; i < 8; i++) {
    int m = m0 + ty * 8 + i;
    float bz = 0.f;
    if (HAS_BIAS) bz = bias[m];
    float4 o0, o1;
    o0.x = acc[i][0] + bz; o0.y = acc[i][1] + bz;
    o0.z = acc[i][2] + bz; o0.w = acc[i][3] + bz;
    o1.x = acc[i][4] + bz; o1.y = acc[i][5] + bz;
    o1.z = acc[i][6] + bz; o1.w = acc[i][7] + bz;
    *(float4*)&Cp[(long)m * N + n0 + tx * 8] = o0;
    *(float4*)&Cp[(long)m * N + n0 + tx * 8 + 4] = o1;
  }
}

// ---------------------------------------------------------------------------
// softmax over d (64 strided elems) for q, then * SCALE.  One thread per n.
// ---------------------------------------------------------------------------
__global__ __launch_bounds__(256) void softmax_q_kernel(float* qkv) {
  const int n = blockIdx.x * 256 + threadIdx.x;
  const int h = blockIdx.y, b = blockIdx.z;
  float* q = qkv + ((long)b * 768 + h * 64) * NPIX + n;
  float v[64];
  float m = -1e30f;
#pragma unroll
  for (int d = 0; d < 64; d++) {
    v[d] = q[(long)d * NPIX];
    m = fmaxf(m, v[d]);
  }
  float s = 0.f;
#pragma unroll
  for (int d = 0; d < 64; d++) {
    v[d] = __expf(v[d] - m);
    s += v[d];
  }
  const float r = SCALE / s;
#pragma unroll
  for (int d = 0; d < 64; d++) q[(long)d * NPIX] = v[d] * r;
}

// ---------------------------------------------------------------------------
// softmax over n (4096 contiguous) for k.  One block per row.
// ---------------------------------------------------------------------------
__global__ __launch_bounds__(256) void softmax_k_kernel(float* qkv) {
  __shared__ float red[4];
  const int r = blockIdx.x;  // h*64+d, 0..255
  const int b = blockIdx.y;
  float* kp = qkv + ((long)b * 768 + 256 + r) * NPIX;
  const int tid = threadIdx.x;
  float v[16];
  float m = -1e30f;
#pragma unroll
  for (int i = 0; i < 16; i++) {
    v[i] = kp[tid + i * 256];
    m = fmaxf(m, v[i]);
  }
#pragma unroll
  for (int off = 32; off >= 1; off >>= 1) m = fmaxf(m, __shfl_down(m, off, 64));
  if ((tid & 63) == 0) red[tid >> 6] = m;
  __syncthreads();
  m = fmaxf(fmaxf(red[0], red[1]), fmaxf(red[2], red[3]));
  __syncthreads();
  float s = 0.f;
#pragma unroll
  for (int i = 0; i < 16; i++) {
    v[i] = __expf(v[i] - m);
    s += v[i];
  }
#pragma unroll
  for (int off = 32; off >= 1; off >>= 1) s += __shfl_down(s, off, 64);
  if ((tid & 63) == 0) red[tid >> 6] = s;
  __syncthreads();
  s = red[0] + red[1] + red[2] + red[3];
  const float inv = 1.0f / s;
#pragma unroll
  for (int i = 0; i < 16; i++) kp[tid + i * 256] = v[i] * inv;
}

__global__ __launch_bounds__(256) void zero_kernel(float* p, int n) {
  int i = blockIdx.x * 256 + threadIdx.x;
  if (i < n) p[i] = 0.f;
}

// ---------------------------------------------------------------------------
// context[b][h][d][e] = sum_n k[d][n] * v[e][n].  n split into 8 chunks of
// 512, partial sums atomically added.  4x4 microtile per thread.
// ---------------------------------------------------------------------------
__global__ __launch_bounds__(256) void context_kernel(const float* __restrict__ qkv,
                                                      float* __restrict__ ctx) {
  const int chunk = blockIdx.x;  // 0..7
  const int h = blockIdx.y, b = blockIdx.z;
  const float* kp = qkv + ((long)b * 768 + 256 + h * 64) * NPIX;
  const float* vp = qkv + ((long)b * 768 + 512 + h * 64) * NPIX;
  __shared__ float ks[64][68];
  __shared__ float vs[64][68];
  const int tid = threadIdx.x;
  const int tx = tid & 15, ty = tid >> 4;
  float acc[4][4];
#pragma unroll
  for (int i = 0; i < 4; i++)
#pragma unroll
    for (int j = 0; j < 4; j++) acc[i][j] = 0.f;

  for (int t = 0; t < 8; t++) {
    const int n0 = chunk * 512 + t * 64;
    __syncthreads();
#pragma unroll
    for (int p = 0; p < 4; p++) {
      int idx = tid + p * 256;  // 0..1023
      int row = idx >> 4;       // 0..63
      int c4 = (idx & 15) * 4;
      *(float4*)&ks[row][c4] = *(const float4*)&kp[(long)row * NPIX + n0 + c4];
      *(float4*)&vs[row][c4] = *(const float4*)&vp[(long)row * NPIX + n0 + c4];
    }
    __syncthreads();
#pragma unroll
    for (int k4 = 0; k4 < 16; k4++) {
      float4 a[4], bb[4];
#pragma unroll
      for (int i = 0; i < 4; i++) a[i] = *(const float4*)&ks[ty * 4 + i][k4 * 4];
#pragma unroll
      for (int j = 0; j < 4; j++) bb[j] = *(const float4*)&vs[tx * 4 + j][k4 * 4];
#pragma unroll
      for (int i = 0; i < 4; i++)
#pragma unroll
        for (int j = 0; j < 4; j++) {
          acc[i][j] += a[i].x * bb[j].x + a[i].y * bb[j].y + a[i].z * bb[j].z +
                       a[i].w * bb[j].w;
        }
    }
  }
  float* cp = ctx + (long)(b * 4 + h) * 4096;
#pragma unroll
  for (int i = 0; i < 4; i++)
#pragma unroll
    for (int j = 0; j < 4; j++)
      atomicAdd(&cp[(ty * 4 + i) * 64 + tx * 4 + j], acc[i][j]);
}

// ---------------------------------------------------------------------------
// out[b][h][e][n] = sum_d ctx[b][h][d][e] * q[b][h][d][n]; writes into the
// (dead) v region of qkv.  One thread per n, ctx read via uniform (scalar)
// loads, 64 accumulators in registers.
// ---------------------------------------------------------------------------
__global__ __launch_bounds__(256) void attnout_kernel(float* __restrict__ qkv,
                                                      const float* __restrict__ ctx) {
  const int n = blockIdx.x * 256 + threadIdx.x;
  const int h = blockIdx.y, b = blockIdx.z;
  const float* qp = qkv + ((long)b * 768 + h * 64) * NPIX;
  float* op = qkv + ((long)b * 768 + 512 + h * 64) * NPIX;
  const float* cp = ctx + (long)(b * 4 + h) * 4096;
  float acc[64];
#pragma unroll
  for (int e = 0; e < 64; e++) acc[e] = 0.f;
  for (int d = 0; d < 64; d++) {
    float qv = qp[(long)d * NPIX + n];
#pragma unroll
    for (int e = 0; e < 64; e++) acc[e] = fmaf(cp[d * 64 + e], qv, acc[e]);
  }
#pragma unroll
  for (int e = 0; e < 64; e++) op[(long)e * NPIX + n] = acc[e];
}

extern "C" void kernel_launch(void* const* d_in, const int* in_sizes, int n_in,
                              void* d_out, int out_size, void* d_ws, size_t ws_size,
                              hipStream_t stream) {
  const float* x = (const float*)d_in[0];      // [16][256][4096]
  const float* w_qkv = (const float*)d_in[1];  // [768][256]
  const float* w_out = (const float*)d_in[2];  // [256][256]
  const float* b_out = (const float*)d_in[3];  // [256]
  float* out = (float*)d_out;                  // [16][256][4096]

  float* qkv = (float*)d_ws;                        // 16*768*4096 floats
  float* ctx = qkv + (long)16 * 768 * NPIX;         // 16*4*64*64 floats

  // 1. qkv = w_qkv @ x  (per batch: [768,256]@[256,4096])
  gemm_kernel<false><<<dim3(32, 6, 16), 256, 0, stream>>>(
      w_qkv, x, qkv, nullptr, 768, NPIX, 256, (long)256 * NPIX, (long)768 * NPIX);
  // 2. q softmax over d, * SCALE (in place)
  softmax_q_kernel<<<dim3(16, 4, 16), 256, 0, stream>>>(qkv);
  // 3. k softmax over n (in place)
  softmax_k_kernel<<<dim3(256, 16), 256, 0, stream>>>(qkv);
  // 4. context = k @ v^T per (b,h)
  zero_kernel<<<dim3(16 * 4 * 64 * 64 / 256), 256, 0, stream>>>(ctx, 16 * 4 * 64 * 64);
  context_kernel<<<dim3(8, 4, 16), 256, 0, stream>>>(qkv, ctx);
  // 5. out = ctx^T @ q per (b,h), overwrites v region
  attnout_kernel<<<dim3(16, 4, 16), 256, 0, stream>>>(qkv, ctx);
  // 6. final = w_out @ out + b_out
  gemm_kernel<true><<<dim3(32, 2, 16), 256, 0, stream>>>(
      w_out, qkv + (long)512 * NPIX, out, b_out, 256, NPIX, 256,
      (long)768 * NPIX, (long)256 * NPIX);
}

// Round 2
// 411.785 us; speedup vs baseline: 1.7174x; 1.7174x over previous
//
#include <hip/hip_runtime.h>

#define NPIX 4096
#define SCALE 0.125f

typedef _Float16 half8 __attribute__((ext_vector_type(8)));
typedef float floatx4 __attribute__((ext_vector_type(4)));

// async global->LDS, 16B per lane. lds must be wave-uniform; data lands at
// lds + lane*16 (gfx950 semantics, learn_hip m97/m104).
__device__ __forceinline__ void async16(void* lds, const void* g) {
  __builtin_amdgcn_global_load_lds(
      (const __attribute__((address_space(1))) unsigned int*)(uintptr_t)g,
      (__attribute__((address_space(3))) unsigned int*)(unsigned)(uintptr_t)lds,
      16, 0, 0);
}

// ---------------------------------------------------------------------------
// split fp32 -> hi/lo fp16 (a = hi + lo with ~21 bits of mantissa kept)
// ---------------------------------------------------------------------------
__global__ __launch_bounds__(256) void split16_kernel(const float* __restrict__ w,
                                                      _Float16* __restrict__ hi,
                                                      _Float16* __restrict__ lo, int n) {
  int i = blockIdx.x * 256 + threadIdx.x;
  if (i < n) {
    float v = w[i];
    _Float16 h = (_Float16)v;
    hi[i] = h;
    lo[i] = (_Float16)(v - (float)h);
  }
}

// ---------------------------------------------------------------------------
// x[b][256][4096] fp32 -> xt[b][4096][256] fp16 (K-contiguous for B-operand)
// ---------------------------------------------------------------------------
__global__ __launch_bounds__(256) void transpose16_kernel(const float* __restrict__ x,
                                                          _Float16* __restrict__ xt) {
  __shared__ float t[64][65];
  const int n0 = blockIdx.x * 64, c0 = blockIdx.y * 64, b = blockIdx.z;
  const float* xp = x + (long)b * 256 * NPIX;
  const int tid = threadIdx.x;
  const int r = tid >> 4, c4 = (tid & 15) * 4;
#pragma unroll
  for (int p = 0; p < 4; p++) {
    float4 v = *(const float4*)&xp[(long)(c0 + r + p * 16) * NPIX + n0 + c4];
    t[r + p * 16][c4 + 0] = v.x;
    t[r + p * 16][c4 + 1] = v.y;
    t[r + p * 16][c4 + 2] = v.z;
    t[r + p * 16][c4 + 3] = v.w;
  }
  __syncthreads();
  const int n = tid >> 2, cg = (tid & 3) * 16;
  alignas(16) _Float16 o[16];
#pragma unroll
  for (int i = 0; i < 16; i++) o[i] = (_Float16)t[cg + i][n];
  _Float16* dst = &xt[((long)b * NPIX + n0 + n) * 256 + c0 + cg];
  *(float4*)dst = *(float4*)&o[0];
  *(float4*)(dst + 8) = *(float4*)&o[8];
}

// ---------------------------------------------------------------------------
// MFMA GEMM: C[b][M][4096] = (Ah+Al)[M][256] * Bt[b][4096][256]^T (+bias)
// BM=BN=128, BK=32, 256 thr = 4 waves in 2x2, each wave 4x4 of 16x16x32 f16.
// 2 MFMAs per tile (a_hi*b + a_lo*b) for near-fp32 accuracy.
// ---------------------------------------------------------------------------
template <bool HAS_BIAS>
__global__ __launch_bounds__(256) void mfma_gemm(const _Float16* __restrict__ Ahp,
                                                 const _Float16* __restrict__ Alp,
                                                 const _Float16* __restrict__ Bt,
                                                 float* __restrict__ C,
                                                 const float* __restrict__ bias,
                                                 long sB, long sC) {
  __shared__ _Float16 sAh[128 * 32];
  __shared__ _Float16 sAl[128 * 32];
  __shared__ _Float16 sBt[128 * 32];
  const int tid = threadIdx.x;
  const int n0 = blockIdx.x * 128, m0 = blockIdx.y * 128;
  const _Float16* Bp = Bt + (long)blockIdx.z * sB;
  float* Cp = C + (long)blockIdx.z * sC;
  const int wv = tid >> 6, l = tid & 63;
  const int r16 = l & 15, q = l >> 4;
  const int mb = (wv >> 1) * 64, nb = (wv & 1) * 64;
  // staging: chunk c covers tile row c>>2, 16B piece (c&3); this thread does
  // chunks tid and tid+256; per-wave-uniform LDS bases.
  const int r1 = tid >> 2, o1 = (tid & 3) * 8;
  const int r2 = r1 + 64, o2 = o1;
  const int ldsc1 = (wv * 64) * 8;
  const int ldsc2 = (256 + wv * 64) * 8;

  floatx4 acc[4][4];
#pragma unroll
  for (int i = 0; i < 4; i++)
#pragma unroll
    for (int j = 0; j < 4; j++) acc[i][j] = (floatx4){0.f, 0.f, 0.f, 0.f};

  for (int kt = 0; kt < 8; kt++) {
    const int k0 = kt * 32;
    async16(&sAh[ldsc1], &Ahp[(long)(m0 + r1) * 256 + k0 + o1]);
    async16(&sAh[ldsc2], &Ahp[(long)(m0 + r2) * 256 + k0 + o2]);
    async16(&sAl[ldsc1], &Alp[(long)(m0 + r1) * 256 + k0 + o1]);
    async16(&sAl[ldsc2], &Alp[(long)(m0 + r2) * 256 + k0 + o2]);
    async16(&sBt[ldsc1], &Bp[(long)(n0 + r1) * 256 + k0 + o1]);
    async16(&sBt[ldsc2], &Bp[(long)(n0 + r2) * 256 + k0 + o2]);
    __syncthreads();
    half8 fa[4], flo[4], fb[4];
#pragma unroll
    for (int i = 0; i < 4; i++) {
      fa[i] = *(const half8*)&sAh[(mb + i * 16 + r16) * 32 + q * 8];
      flo[i] = *(const half8*)&sAl[(mb + i * 16 + r16) * 32 + q * 8];
      fb[i] = *(const half8*)&sBt[(nb + i * 16 + r16) * 32 + q * 8];
    }
#pragma unroll
    for (int i = 0; i < 4; i++)
#pragma unroll
      for (int j = 0; j < 4; j++) {
        acc[i][j] = __builtin_amdgcn_mfma_f32_16x16x32_f16(fa[i], fb[j], acc[i][j], 0, 0, 0);
        acc[i][j] = __builtin_amdgcn_mfma_f32_16x16x32_f16(flo[i], fb[j], acc[i][j], 0, 0, 0);
      }
    __syncthreads();
  }
  // C/D layout: col = lane&15, row = (lane>>4)*4 + reg  (learn_hip m89)
#pragma unroll
  for (int i = 0; i < 4; i++) {
    const int mrow = m0 + mb + i * 16 + q * 4;
#pragma unroll
    for (int t = 0; t < 4; t++) {
      float bz = HAS_BIAS ? bias[mrow + t] : 0.f;
#pragma unroll
      for (int j = 0; j < 4; j++) {
        Cp[(long)(mrow + t) * NPIX + n0 + nb + j * 16 + r16] = acc[i][j][t] + bz;
      }
    }
  }
}

// ---------------------------------------------------------------------------
// softmax over d (64 strided elems) for q, then * SCALE.  One thread per n.
// ---------------------------------------------------------------------------
__global__ __launch_bounds__(256) void softmax_q_kernel(float* qkv) {
  const int n = blockIdx.x * 256 + threadIdx.x;
  const int h = blockIdx.y, b = blockIdx.z;
  float* q = qkv + ((long)b * 768 + h * 64) * NPIX + n;
  float v[64];
  float m = -1e30f;
#pragma unroll
  for (int d = 0; d < 64; d++) {
    v[d] = q[(long)d * NPIX];
    m = fmaxf(m, v[d]);
  }
  float s = 0.f;
#pragma unroll
  for (int d = 0; d < 64; d++) {
    v[d] = __expf(v[d] - m);
    s += v[d];
  }
  const float r = SCALE / s;
#pragma unroll
  for (int d = 0; d < 64; d++) q[(long)d * NPIX] = v[d] * r;
}

// ---------------------------------------------------------------------------
// softmax over n (4096 contiguous) for k.  One block per row.
// ---------------------------------------------------------------------------
__global__ __launch_bounds__(256) void softmax_k_kernel(float* qkv) {
  __shared__ float red[4];
  const int r = blockIdx.x;
  const int b = blockIdx.y;
  float* kp = qkv + ((long)b * 768 + 256 + r) * NPIX;
  const int tid = threadIdx.x;
  float v[16];
  float m = -1e30f;
#pragma unroll
  for (int i = 0; i < 16; i++) {
    v[i] = kp[tid + i * 256];
    m = fmaxf(m, v[i]);
  }
#pragma unroll
  for (int off = 32; off >= 1; off >>= 1) m = fmaxf(m, __shfl_down(m, off, 64));
  if ((tid & 63) == 0) red[tid >> 6] = m;
  __syncthreads();
  m = fmaxf(fmaxf(red[0], red[1]), fmaxf(red[2], red[3]));
  __syncthreads();
  float s = 0.f;
#pragma unroll
  for (int i = 0; i < 16; i++) {
    v[i] = __expf(v[i] - m);
    s += v[i];
  }
#pragma unroll
  for (int off = 32; off >= 1; off >>= 1) s += __shfl_down(s, off, 64);
  if ((tid & 63) == 0) red[tid >> 6] = s;
  __syncthreads();
  s = red[0] + red[1] + red[2] + red[3];
  const float inv = 1.0f / s;
#pragma unroll
  for (int i = 0; i < 16; i++) kp[tid + i * 256] = v[i] * inv;
}

__global__ __launch_bounds__(256) void zero_kernel(float* p, int n) {
  int i = blockIdx.x * 256 + threadIdx.x;
  if (i < n) p[i] = 0.f;
}

// ---------------------------------------------------------------------------
// context[b][h][d][e] = sum_n k[d][n] * v[e][n].  8 n-chunks, atomicAdd.
// ---------------------------------------------------------------------------
__global__ __launch_bounds__(256) void context_kernel(const float* __restrict__ qkv,
                                                      float* __restrict__ ctx) {
  const int chunk = blockIdx.x;
  const int h = blockIdx.y, b = blockIdx.z;
  const float* kp = qkv + ((long)b * 768 + 256 + h * 64) * NPIX;
  const float* vp = qkv + ((long)b * 768 + 512 + h * 64) * NPIX;
  __shared__ float ks[64][68];
  __shared__ float vs[64][68];
  const int tid = threadIdx.x;
  const int tx = tid & 15, ty = tid >> 4;
  float acc[4][4];
#pragma unroll
  for (int i = 0; i < 4; i++)
#pragma unroll
    for (int j = 0; j < 4; j++) acc[i][j] = 0.f;

  for (int t = 0; t < 8; t++) {
    const int n0 = chunk * 512 + t * 64;
    __syncthreads();
#pragma unroll
    for (int p = 0; p < 4; p++) {
      int idx = tid + p * 256;
      int row = idx >> 4;
      int c4 = (idx & 15) * 4;
      *(float4*)&ks[row][c4] = *(const float4*)&kp[(long)row * NPIX + n0 + c4];
      *(float4*)&vs[row][c4] = *(const float4*)&vp[(long)row * NPIX + n0 + c4];
    }
    __syncthreads();
#pragma unroll
    for (int k4 = 0; k4 < 16; k4++) {
      float4 a[4], bb[4];
#pragma unroll
      for (int i = 0; i < 4; i++) a[i] = *(const float4*)&ks[ty * 4 + i][k4 * 4];
#pragma unroll
      for (int j = 0; j < 4; j++) bb[j] = *(const float4*)&vs[tx * 4 + j][k4 * 4];
#pragma unroll
      for (int i = 0; i < 4; i++)
#pragma unroll
        for (int j = 0; j < 4; j++) {
          acc[i][j] += a[i].x * bb[j].x + a[i].y * bb[j].y + a[i].z * bb[j].z +
                       a[i].w * bb[j].w;
        }
    }
  }
  float* cp = ctx + (long)(b * 4 + h) * 4096;
#pragma unroll
  for (int i = 0; i < 4; i++)
#pragma unroll
    for (int j = 0; j < 4; j++)
      atomicAdd(&cp[(ty * 4 + i) * 64 + tx * 4 + j], acc[i][j]);
}

// ---------------------------------------------------------------------------
// out[b][n][h*64+e] (fp16, transposed) = sum_d ctx[d][e] * q[d][n]
// ---------------------------------------------------------------------------
__global__ __launch_bounds__(256) void attnout_kernel(const float* __restrict__ qkv,
                                                      const float* __restrict__ ctx,
                                                      _Float16* __restrict__ attn) {
  const int n = blockIdx.x * 256 + threadIdx.x;
  const int h = blockIdx.y, b = blockIdx.z;
  const float* qp = qkv + ((long)b * 768 + h * 64) * NPIX;
  const float* cp = ctx + (long)(b * 4 + h) * 4096;
  float acc[64];
#pragma unroll
  for (int e = 0; e < 64; e++) acc[e] = 0.f;
  for (int d = 0; d < 64; d++) {
    float qv = qp[(long)d * NPIX + n];
#pragma unroll
    for (int e = 0; e < 64; e++) acc[e] = fmaf(cp[d * 64 + e], qv, acc[e]);
  }
  alignas(16) _Float16 tmp[64];
#pragma unroll
  for (int e = 0; e < 64; e++) tmp[e] = (_Float16)acc[e];
  _Float16* op = attn + (long)b * 768 * NPIX * 2 + (long)n * 256 + h * 64;
#pragma unroll
  for (int p = 0; p < 8; p++) ((float4*)op)[p] = ((float4*)tmp)[p];
}

extern "C" void kernel_launch(void* const* d_in, const int* in_sizes, int n_in,
                              void* d_out, int out_size, void* d_ws, size_t ws_size,
                              hipStream_t stream) {
  const float* x = (const float*)d_in[0];      // [16][256][4096]
  const float* w_qkv = (const float*)d_in[1];  // [768][256]
  const float* w_out = (const float*)d_in[2];  // [256][256]
  const float* b_out = (const float*)d_in[3];  // [256]
  float* out = (float*)d_out;                  // [16][256][4096]

  float* qkv = (float*)d_ws;                          // 192 MB fp32
  float* ctx = qkv + (long)16 * 768 * NPIX;           // 1 MB
  _Float16* wq_hi = (_Float16*)(ctx + 16 * 4 * 64 * 64);
  _Float16* wq_lo = wq_hi + 768 * 256;
  _Float16* wo_hi = wq_lo + 768 * 256;
  _Float16* wo_lo = wo_hi + 256 * 256;
  _Float16* xt = (_Float16*)d_out;                    // 32 MB scratch in d_out (dead before final GEMM)
  _Float16* attn16 = (_Float16*)(qkv + (long)512 * NPIX);  // in dead v-region of qkv

  split16_kernel<<<768, 256, 0, stream>>>(w_qkv, wq_hi, wq_lo, 768 * 256);
  split16_kernel<<<256, 256, 0, stream>>>(w_out, wo_hi, wo_lo, 256 * 256);
  // xt[b][n][c] fp16
  transpose16_kernel<<<dim3(64, 4, 16), 256, 0, stream>>>(x, xt);
  // qkv = w_qkv @ x  (fp16 split-A MFMA, fp32 out)
  mfma_gemm<false><<<dim3(32, 6, 16), 256, 0, stream>>>(
      wq_hi, wq_lo, xt, qkv, nullptr, (long)NPIX * 256, (long)768 * NPIX);
  softmax_q_kernel<<<dim3(16, 4, 16), 256, 0, stream>>>(qkv);
  softmax_k_kernel<<<dim3(256, 16), 256, 0, stream>>>(qkv);
  zero_kernel<<<dim3(16 * 4 * 64 * 64 / 256), 256, 0, stream>>>(ctx, 16 * 4 * 64 * 64);
  context_kernel<<<dim3(8, 4, 16), 256, 0, stream>>>(qkv, ctx);
  // attn (fp16, [n][256] per batch) into dead v-region
  attnout_kernel<<<dim3(16, 4, 16), 256, 0, stream>>>(qkv, ctx, attn16);
  // final = w_out @ attn + b_out
  mfma_gemm<true><<<dim3(32, 2, 16), 256, 0, stream>>>(
      wo_hi, wo_lo, attn16, out, b_out, (long)768 * NPIX * 2, (long)256 * NPIX);
}